// Round 7
// baseline (705.242 us; speedup 1.0000x reference)
//
#include <hip/hip_runtime.h>

#define N_NODES 100000
#define N_EDGES 1600000
#define D_IN    256
#define D_HID   64
#define D_OUT   32
#define NPROP   10

#define NBUCK 196          // bucket = row >> 9 (512 rows/bucket)
#define CHUNK 6080         // edges per bscatter block (LDS-limited)
#define NCHUNK ((N_EDGES + CHUNK - 1) / CHUNK)   // 264

typedef _Float16 half_t;
typedef _Float16 h8  __attribute__((ext_vector_type(8)));
typedef _Float16 h4  __attribute__((ext_vector_type(4)));
typedef float    f4v __attribute__((ext_vector_type(4)));
typedef unsigned long long u64;

union u16h { unsigned short s; half_t h; };

// ---------------- weight pack ----------------
__global__ __launch_bounds__(256) void pack_kernel(
    const float* __restrict__ W1, const float* __restrict__ W2,
    half_t* __restrict__ W1T, half_t* __restrict__ W2T)
{
  int t = blockIdx.x * 256 + threadIdx.x;
  if (t < 64 * 256) { int n = t >> 8, k = t & 255; W1T[t] = (half_t)W1[k * 64 + n]; }
  if (t < 32 * 64)  { int n = t >> 6, k = t & 63;  W2T[t] = (half_t)W2[k * 32 + n]; }
}

// ---------------- MLP head via MFMA v2 ----------------
// Block = 64 nodes, 4 waves; wave w owns nodes [w*16, w*16+16) x FULL K=256
// (round-5 profile: VGPR=16 -> serial load/mfma chain + 4x redundant A loads).
// All 16 A-loads staged in registers first -> 16 VMEM in flight per wave.
// Wave computes all 64 hid cols (4 MFMA frags), h -> LDS, layer 2 (2 frags),
// split-store x0 into lo/hi 16-channel half-tables (for channel-blocked prop).
__global__ __launch_bounds__(256) void mlp_kernel(
    const float* __restrict__ F, const half_t* __restrict__ W1T,
    const float* __restrict__ b1, const half_t* __restrict__ W2T,
    const float* __restrict__ b2, half_t* __restrict__ x0L,
    half_t* __restrict__ x0H)
{
  __shared__ half_t h_lds[64 * 72];    // 64 nodes x 64 hid, pad 72
  __shared__ half_t out_lds[64 * 32];
  int t = threadIdx.x;
  int w = t >> 6, lane = t & 63;
  int m = lane & 15, q = lane >> 4;
  int nodeb = blockIdx.x * 64;
  int node0 = nodeb + w * 16;
  int nc = min(node0 + m, N_NODES - 1);
  const float* arow = F + (size_t)nc * D_IN + q * 8;

  // stage all 16 A-loads (this lane's full K row-slice)
  float4 fa[16];
#pragma unroll
  for (int s = 0; s < 8; ++s) {
    fa[2 * s]     = *(const float4*)(arow + s * 32);
    fa[2 * s + 1] = *(const float4*)(arow + s * 32 + 4);
  }

  f4v acc[4];
#pragma unroll
  for (int g = 0; g < 4; ++g) acc[g] = (f4v){0.f, 0.f, 0.f, 0.f};

#pragma unroll
  for (int s = 0; s < 8; ++s) {
    float4 f0 = fa[2 * s], f1 = fa[2 * s + 1];
    h8 a;
    a[0] = (_Float16)f0.x; a[1] = (_Float16)f0.y;
    a[2] = (_Float16)f0.z; a[3] = (_Float16)f0.w;
    a[4] = (_Float16)f1.x; a[5] = (_Float16)f1.y;
    a[6] = (_Float16)f1.z; a[7] = (_Float16)f1.w;
#pragma unroll
    for (int g = 0; g < 4; ++g) {
      h8 b = *(const h8*)(W1T + (size_t)(g * 16 + m) * D_IN + s * 32 + q * 8);
      acc[g] = __builtin_amdgcn_mfma_f32_16x16x32_f16(a, b, acc[g], 0, 0, 0);
    }
  }

  // bias + relu -> h_lds (frag g: hid col g*16+m, node rows q*4+i)
#pragma unroll
  for (int g = 0; g < 4; ++g) {
    float bb = b1[g * 16 + m];
#pragma unroll
    for (int i = 0; i < 4; ++i)
      h_lds[(w * 16 + q * 4 + i) * 72 + g * 16 + m] =
          (half_t)fmaxf(acc[g][i] + bb, 0.f);
  }
  __syncthreads();

  // layer 2: wave w does its 16 nodes, N=32 (2 frags), K=64 (2 steps)
  f4v acc2[2];
  acc2[0] = (f4v){0.f, 0.f, 0.f, 0.f};
  acc2[1] = (f4v){0.f, 0.f, 0.f, 0.f};
#pragma unroll
  for (int s = 0; s < 2; ++s) {
    h8 a = *(const h8*)(h_lds + (w * 16 + m) * 72 + s * 32 + q * 8);
#pragma unroll
    for (int g = 0; g < 2; ++g) {
      h8 b = *(const h8*)(W2T + (size_t)(g * 16 + m) * D_HID + s * 32 + q * 8);
      acc2[g] = __builtin_amdgcn_mfma_f32_16x16x32_f16(a, b, acc2[g], 0, 0, 0);
    }
  }
#pragma unroll
  for (int g = 0; g < 2; ++g) {
    float b2v = b2[g * 16 + m];
#pragma unroll
    for (int i = 0; i < 4; ++i)
      out_lds[(w * 16 + q * 4 + i) * 32 + g * 16 + m] = (half_t)(acc2[g][i] + b2v);
  }
  __syncthreads();

  // split store: 64 nodes x (lo 16ch | hi 16ch); one int4 (8 halves) per thread
  {
    int nl = t >> 2, qq = t & 3;
    int node = nodeb + nl;
    if (node < N_NODES) {
      int4 v = *(const int4*)(out_lds + nl * 32 + qq * 8);
      if (qq < 2)
        *(int4*)(x0L + (size_t)node * 16 + qq * 8) = v;
      else
        *(int4*)(x0H + (size_t)node * 16 + (qq - 2) * 8) = v;
    }
  }
}

// ---------------- CSR build, two-pass bucketed sort (round-5, known-good) ----------------
__global__ __launch_bounds__(256) void bhist_kernel(
    const int* __restrict__ row, int* __restrict__ bcnt)
{
  __shared__ int lb[NBUCK];
  int t = threadIdx.x;
  for (int i = t; i < NBUCK; i += 256) lb[i] = 0;
  __syncthreads();
  int stride = gridDim.x * 256;
  for (int e = blockIdx.x * 256 + t; e < N_EDGES; e += stride)
    atomicAdd(&lb[row[e] >> 9], 1);
  __syncthreads();
  for (int i = t; i < NBUCK; i += 256)
    if (lb[i]) atomicAdd(&bcnt[i], lb[i]);
}

__global__ __launch_bounds__(256) void bscan_kernel(
    const int* __restrict__ bcnt, int* __restrict__ bbase, int* __restrict__ pbase)
{
  __shared__ int l1[256], l2[256];
  int t = threadIdx.x;
  int a = (t < NBUCK) ? bcnt[t] : 0;
  int r = (t < NBUCK) ? (((a + 3) & ~3) + 3 * 512) : 0;
  l1[t] = a; l2[t] = r;
  __syncthreads();
  for (int off = 1; off < 256; off <<= 1) {
    int x1 = (t >= off) ? l1[t - off] : 0;
    int x2 = (t >= off) ? l2[t - off] : 0;
    __syncthreads();
    l1[t] += x1; l2[t] += x2;
    __syncthreads();
  }
  if (t < NBUCK) { bbase[t] = l1[t] - a; pbase[t] = l2[t] - r; }
  if (t == NBUCK - 1) { bbase[NBUCK] = l1[t]; pbase[NBUCK] = l2[t]; }
}

__global__ __launch_bounds__(256) void bscatter_kernel(
    const int* __restrict__ row, const int* __restrict__ col,
    const float* __restrict__ vals, int* __restrict__ bfill,
    const int* __restrict__ bbase, int2* __restrict__ ebuck)
{
  __shared__ int2 img[CHUNK];
  __shared__ unsigned short sbk[CHUNK];
  __shared__ int cnt[NBUCK], base[NBUCK], gb[NBUCK], fil[NBUCK];
  __shared__ int ssc[256];
  int t = threadIdx.x;
  int e0 = blockIdx.x * CHUNK;
  int n = min(CHUNK, N_EDGES - e0);

  for (int i = t; i < NBUCK; i += 256) { cnt[i] = 0; fil[i] = 0; }
  __syncthreads();
  for (int i = t; i < n; i += 256) atomicAdd(&cnt[row[e0 + i] >> 9], 1);
  __syncthreads();
  int c = (t < NBUCK) ? cnt[t] : 0;
  ssc[t] = c;
  __syncthreads();
  for (int off = 1; off < 256; off <<= 1) {
    int add = (t >= off) ? ssc[t - off] : 0;
    __syncthreads();
    ssc[t] += add;
    __syncthreads();
  }
  if (t < NBUCK) {
    base[t] = ssc[t] - c;
    gb[t] = c ? atomicAdd(&bfill[t], c) : 0;
  }
  __syncthreads();
  for (int i = t; i < n; i += 256) {
    int r = row[e0 + i];
    int bk = r >> 9;
    int p = base[bk] + atomicAdd(&fil[bk], 1);
    img[p] = make_int2(col[e0 + i] | ((r & 511) << 17),
                       __float_as_int(vals[e0 + i]));
    sbk[p] = (unsigned short)bk;
  }
  __syncthreads();
  for (int i = t; i < n; i += 256) {
    int bk = sbk[i];
    ebuck[bbase[bk] + gb[bk] + (i - base[bk])] = img[i];
  }
}

// K5: per-bucket exact sort + pad. Emits row_ptr and PACKED 4B edges:
// edge dword = (col << 15) | (fp16(val) & 0x7FFF)  (val > 0 -> sign bit free).
// Halves the ep stream the spmm re-reads 20x.
__global__ __launch_bounds__(256) void bsort_kernel(
    const int* __restrict__ bbase, const int* __restrict__ pbase,
    const int2* __restrict__ ebuck, unsigned* __restrict__ epack,
    int* __restrict__ row_ptr)
{
  __shared__ int acnt[512], loff[513], lfill[512], ssc[256];
  int b = blockIdx.x, t = threadIdx.x;
  int r0 = b * 512;
  int nr = min(512, N_NODES - r0);
  int eb = bbase[b];
  int ne = bbase[b + 1] - eb;
  int pb = pbase[b];

  acnt[t] = 0; acnt[t + 256] = 0;
  lfill[t] = 0; lfill[t + 256] = 0;
  __syncthreads();
  for (int i = t; i < ne; i += 256)
    atomicAdd(&acnt[((unsigned)ebuck[eb + i].x) >> 17], 1);
  __syncthreads();
  int i0 = 2 * t, i1 = 2 * t + 1;
  int a0 = acnt[i0], a1 = acnt[i1];
  int p0 = (a0 + 3) & ~3, p1 = (a1 + 3) & ~3;
  int s = p0 + p1;
  ssc[t] = s;
  __syncthreads();
  for (int off = 1; off < 256; off <<= 1) {
    int add = (t >= off) ? ssc[t - off] : 0;
    __syncthreads();
    ssc[t] += add;
    __syncthreads();
  }
  int ex = ssc[t] - s;
  loff[i0] = ex;
  loff[i1] = ex + p0;
  if (t == 255) loff[512] = ssc[255];
  __syncthreads();
  int T = ssc[255];
  int slack = (pbase[b + 1] - pb) - T;
  int units = min(slack >> 2, nr);
  if (i0 < nr) row_ptr[r0 + i0] = pb + loff[i0] + 4 * min(i0, units);
  if (i1 < nr) row_ptr[r0 + i1] = pb + loff[i1] + 4 * min(i1, units);
  if (b == NBUCK - 1 && t == 0)
    row_ptr[N_NODES] = pb + loff[nr] + 4 * units;
  __syncthreads();
  for (int i = t; i < ne; i += 256) {
    int2 ed = ebuck[eb + i];
    int lr = ((unsigned)ed.x) >> 17;
    int cl = ed.x & 0x1FFFF;
    int p = loff[lr] + 4 * min(lr, units) + atomicAdd(&lfill[lr], 1);
    u16h cv; cv.h = (half_t)__int_as_float(ed.y);
    epack[pb + p] = ((unsigned)cl << 15) | (unsigned)(cv.s & 0x7FFF);
  }
  __syncthreads();
  for (int i = t; i < nr; i += 256) {
    int a = acnt[i];
    int size_i = ((a + 3) & ~3) + 4 * (i < units);
    int st = loff[i] + 4 * min(i, units);
    for (int p = st + a; p < st + size_i; ++p)
      epack[pb + p] = 0u;   // col 0, val +0
  }
}

// ---------------- channel-blocked propagation ----------------
// One 16-channel half-table (3.2 MB) per 10-iteration sequence -> fits every
// XCD's 4 MB L2 -> gathers are ~200-cyc L2 hits instead of ~600-cyc L3
// (round-5 model: spmm is latency x concurrency bound). 4 lanes/row x 4 ch.
// ep/x0 streams use non-temporal loads to protect table residency in L2.
// Rows padded to multiples of 4: 8-edge staged blocks + optional one 4-block.
__global__ __launch_bounds__(256) void spmm_kernel(
    const int* __restrict__ rp, const unsigned* __restrict__ ep,
    const half_t* __restrict__ xin,   // [N][16] half-table
    const half_t* __restrict__ x0h,   // [N][16]
    half_t* __restrict__ xout, float* __restrict__ fout, int last)
{
  int gt = blockIdx.x * 256 + threadIdx.x;
  int r = gt >> 2;
  int c4 = (gt & 3) * 4;
  if (r >= N_NODES) return;
  int e0 = rp[r], e1 = rp[r + 1];

  float acc[4] = {0.f, 0.f, 0.f, 0.f};
  int e = e0;
  for (; e + 7 < e1; e += 8) {
    unsigned u0 = __builtin_nontemporal_load(ep + e);
    unsigned u1 = __builtin_nontemporal_load(ep + e + 1);
    unsigned u2 = __builtin_nontemporal_load(ep + e + 2);
    unsigned u3 = __builtin_nontemporal_load(ep + e + 3);
    unsigned u4 = __builtin_nontemporal_load(ep + e + 4);
    unsigned u5 = __builtin_nontemporal_load(ep + e + 5);
    unsigned u6 = __builtin_nontemporal_load(ep + e + 6);
    unsigned u7 = __builtin_nontemporal_load(ep + e + 7);
    h4 g0 = *(const h4*)(xin + (size_t)(u0 >> 15) * 16 + c4);
    h4 g1 = *(const h4*)(xin + (size_t)(u1 >> 15) * 16 + c4);
    h4 g2 = *(const h4*)(xin + (size_t)(u2 >> 15) * 16 + c4);
    h4 g3 = *(const h4*)(xin + (size_t)(u3 >> 15) * 16 + c4);
    h4 g4 = *(const h4*)(xin + (size_t)(u4 >> 15) * 16 + c4);
    h4 g5 = *(const h4*)(xin + (size_t)(u5 >> 15) * 16 + c4);
    h4 g6 = *(const h4*)(xin + (size_t)(u6 >> 15) * 16 + c4);
    h4 g7 = *(const h4*)(xin + (size_t)(u7 >> 15) * 16 + c4);
    u16h v0, v1, v2, v3, v4, v5, v6, v7;
    v0.s = u0 & 0x7FFF; v1.s = u1 & 0x7FFF; v2.s = u2 & 0x7FFF; v3.s = u3 & 0x7FFF;
    v4.s = u4 & 0x7FFF; v5.s = u5 & 0x7FFF; v6.s = u6 & 0x7FFF; v7.s = u7 & 0x7FFF;
#pragma unroll
    for (int j = 0; j < 4; ++j) {
      acc[j] = fmaf((float)v0.h, (float)g0[j], acc[j]);
      acc[j] = fmaf((float)v1.h, (float)g1[j], acc[j]);
      acc[j] = fmaf((float)v2.h, (float)g2[j], acc[j]);
      acc[j] = fmaf((float)v3.h, (float)g3[j], acc[j]);
      acc[j] = fmaf((float)v4.h, (float)g4[j], acc[j]);
      acc[j] = fmaf((float)v5.h, (float)g5[j], acc[j]);
      acc[j] = fmaf((float)v6.h, (float)g6[j], acc[j]);
      acc[j] = fmaf((float)v7.h, (float)g7[j], acc[j]);
    }
  }
  if (e < e1) {   // exactly 4 remain (degrees padded to multiples of 4)
    unsigned u0 = __builtin_nontemporal_load(ep + e);
    unsigned u1 = __builtin_nontemporal_load(ep + e + 1);
    unsigned u2 = __builtin_nontemporal_load(ep + e + 2);
    unsigned u3 = __builtin_nontemporal_load(ep + e + 3);
    h4 g0 = *(const h4*)(xin + (size_t)(u0 >> 15) * 16 + c4);
    h4 g1 = *(const h4*)(xin + (size_t)(u1 >> 15) * 16 + c4);
    h4 g2 = *(const h4*)(xin + (size_t)(u2 >> 15) * 16 + c4);
    h4 g3 = *(const h4*)(xin + (size_t)(u3 >> 15) * 16 + c4);
    u16h v0, v1, v2, v3;
    v0.s = u0 & 0x7FFF; v1.s = u1 & 0x7FFF; v2.s = u2 & 0x7FFF; v3.s = u3 & 0x7FFF;
#pragma unroll
    for (int j = 0; j < 4; ++j) {
      acc[j] = fmaf((float)v0.h, (float)g0[j], acc[j]);
      acc[j] = fmaf((float)v1.h, (float)g1[j], acc[j]);
      acc[j] = fmaf((float)v2.h, (float)g2[j], acc[j]);
      acc[j] = fmaf((float)v3.h, (float)g3[j], acc[j]);
    }
  }

  u64 raw = __builtin_nontemporal_load((const u64*)(x0h + (size_t)r * 16 + c4));
  h4 x0v = *(h4*)&raw;
  if (last) {
    float4 o;
    o.x = 0.9f * acc[0] + 0.1f * (float)x0v[0];
    o.y = 0.9f * acc[1] + 0.1f * (float)x0v[1];
    o.z = 0.9f * acc[2] + 0.1f * (float)x0v[2];
    o.w = 0.9f * acc[3] + 0.1f * (float)x0v[3];
    *(float4*)(fout + (size_t)r * D_OUT + c4) = o;
  } else {
    h4 o;
#pragma unroll
    for (int j = 0; j < 4; ++j)
      o[j] = (half_t)(0.9f * acc[j] + 0.1f * (float)x0v[j]);
    *(h4*)(xout + (size_t)r * 16 + c4) = o;
  }
}

extern "C" void kernel_launch(void* const* d_in, const int* in_sizes, int n_in,
                              void* d_out, int out_size, void* d_ws, size_t ws_size,
                              hipStream_t stream) {
  const float* F     = (const float*)d_in[0];
  const int*   row   = (const int*)  d_in[1];
  const int*   col   = (const int*)  d_in[2];
  const float* evals = (const float*)d_in[3];
  const float* W1    = (const float*)d_in[4];
  const float* b1    = (const float*)d_in[5];
  const float* W2    = (const float*)d_in[6];
  const float* b2    = (const float*)d_in[7];
  float* out = (float*)d_out;

  // workspace (~27.4 MB). PL/QL/PH/QH alias ebuck (ebuck is dead before the
  // first spmm write, stream-ordered). NOTE: no trailing backslashes here.
  char* w = (char*)d_ws;
  half_t* x0L    = (half_t*)(w);                // 3,200,000
  half_t* x0H    = (half_t*)(w +  3200000);     // 3,200,000
  half_t* PL     = (half_t*)(w +  6400000);     // 3,200,000 (alias ebuck)
  half_t* QL     = (half_t*)(w +  9600000);     // 3,200,000 (alias ebuck)
  half_t* PH     = (half_t*)(w + 12800000);     // 3,200,000 (alias ebuck)
  half_t* QH     = (half_t*)(w + 16000000);     // 3,200,000 (alias ebuck)
  int2*   ebuck  = (int2*)  (w +  6400000);     // 12,800,000
  unsigned* epack= (unsigned*)(w + 19200000);   // 7,700,000 (padded 4B edges)
  int*   row_ptr = (int*)   (w + 26900224);     // 400,128 (N+1)
  int*   bcnt    = (int*)   (w + 27300352);     // 1,024 (zeroed)
  int*   bfill   = (int*)   (w + 27301376);     // 1,024 (zeroed)
  int*   bbase   = (int*)   (w + 27302400);     // 1,024
  int*   pbase   = (int*)   (w + 27303424);     // 1,024
  half_t* W1T    = (half_t*)(w + 27304448);     // 32,768
  half_t* W2T    = (half_t*)(w + 27337216);     // 4,096

  // 1) MLP head -> x0 split into lo/hi half-tables
  pack_kernel<<<64, 256, 0, stream>>>(W1, W2, W1T, W2T);
  mlp_kernel<<<(N_NODES + 63) / 64, 256, 0, stream>>>(F, W1T, b1, W2T, b2, x0L, x0H);

  // 2) CSR build (bucketed two-pass sort, padded rows, packed 4B edges)
  (void)hipMemsetAsync(bcnt, 0, 2048, stream);   // bcnt + bfill
  bhist_kernel<<<640, 256, 0, stream>>>(row, bcnt);
  bscan_kernel<<<1, 256, 0, stream>>>(bcnt, bbase, pbase);
  bscatter_kernel<<<NCHUNK, 256, 0, stream>>>(row, col, evals, bfill, bbase, ebuck);
  bsort_kernel<<<NBUCK, 256, 0, stream>>>(bbase, pbase, ebuck, epack, row_ptr);

  // 3) channel-blocked propagation: 10 iters on lo half, then 10 on hi half
  const int grid_spmm = (N_NODES * 4 + 255) / 256;
  for (int h = 0; h < 2; ++h) {
    const half_t* x0h = h ? x0H : x0L;
    half_t* Ph = h ? PH : PL;
    half_t* Qh = h ? QH : QL;
    float* fo = out + h * 16;
    for (int i = 0; i < NPROP; ++i) {
      const half_t* xin = (i == 0) ? x0h : ((i & 1) ? Ph : Qh);
      half_t* xout = (i & 1) ? Qh : Ph;
      spmm_kernel<<<grid_spmm, 256, 0, stream>>>(
          row_ptr, epack, xin, x0h, xout, fo, i == NPROP - 1);
    }
  }
}